// Round 9
// baseline (2437.551 us; speedup 1.0000x reference)
//
#include <hip/hip_runtime.h>
#include <cstdint>

// Cortex reservoir: embed(perm-gather) -> single-XCD persistent wave-autonomous
// spiking scan (tagged-data sync at L2 scope) -> chunked dense readout GEMM.
//
// Scan sync (R6's verified mechanism, verbatim): lane's 4 S-cells pack into ONE
// dword pk = S0|S1<<4|S2<<8|S3<<12|(t+1)<<16 (nibbles + step tag).
// Publish = plain VOLATILE store (write-through L1 -> XCD-0 L2). Poll =
// buffer_inv (drop stale L1) + volatile dword loads, retried until all 10 tap
// tags match. Tag travels WITH the data -> no fences, no vmcnt drains.
// Tap set {+-1,+-2,+-4,+-6,+-8} symmetric -> ping-pong race-free.
//
// R9 composition (from the R3..R8 counter matrix): the R3-family's 7300cy/step
// floor was sc0+sc1 agent-scope sync routing EVERY poll through the Infinity
// Cache (FETCH_SIZE 5.6MB = poll volume); R6's L2-scope sync was correct but
// its PLAIN Achunk stores evicted Spub from the 4MiB L2 -> polls missed to HBM
// (FETCH 4.9MB, 540us). Fix = combine both verified halves: L2-scope sync
// (R6) + nontemporal bf16 readout stores (R8's bf16 plane + R4's nt idiom) so
// the 32MB/chunk store stream never allocates in L2. Spub (128KB) stays
// L2-resident; publish->observe becomes ~one L2 RTT.
//
// ws layout (~41 MiB):
//   OFF_PERM  : perm int[1024]
//   OFF_FLAG  : ticket at int[1024]
//   OFF_VSAVE : V snapshot float[65536]
//   OFF_S     : Spub packed ping-pong uint[2][256][64]
//   OFF_A     : A chunk bf16[128][131072]
//   OFF_P     : split-K partials float[128][128][128]

namespace {

constexpr int TT = 512;
constexpr int DD = 256;
constexpr int CELLS = DD * DD;              // 65536
constexpr long KTOT = 2L * CELLS;           // 131072
constexpr int TB = 128;                     // time-chunk
constexpr int NCH = TT / TB;                // 4
constexpr int KSLAB = 1024;
constexpr int NSLAB = 128;                  // KTOT / KSLAB
constexpr int NW = 64;                      // worker blocks (one XCD)

constexpr long OFF_PERM = 0;
constexpr long OFF_FLAG = 4096;
constexpr long OFF_VSAVE = OFF_FLAG + 8192;
constexpr long OFF_S = OFF_VSAVE + (long)CELLS * 4;
constexpr long OFF_A = OFF_S + 2L * CELLS * 4;
constexpr long OFF_P = OFF_A + (long)TB * KTOT * 2;        // bf16 A plane
constexpr long WS_REQUIRED = OFF_P + (long)NSLAB * TB * 128 * 4;  // ~41 MiB

typedef unsigned short u16x4 __attribute__((ext_vector_type(4)));

__device__ __forceinline__ int xcc_id() {
    int x;
    asm volatile("s_getreg_b32 %0, hwreg(HW_REG_XCC_ID, 0, 4)" : "=s"(x));
    return x;
}

// fp32 -> bf16 bits, round-to-nearest-even (values are finite here).
__device__ __forceinline__ unsigned short f2bf(float x) {
    unsigned int u = __float_as_uint(x);
    u += 0x7FFFu + ((u >> 16) & 1u);
    return (unsigned short)(u >> 16);
}
// bf16 bits -> fp32 (exact).
__device__ __forceinline__ float bf2f(unsigned short b) {
    return __uint_as_float((unsigned int)b << 16);
}

// nontemporal (evict-first) 8B store of 4 bf16 — keeps the streaming readout
// plane OUT of the XCD-0 L2 so Spub stays resident.
__device__ __forceinline__ void nt_store_bf4(unsigned short* p, u16x4 v) {
    __builtin_nontemporal_store(v, (u16x4*)p);
}

__global__ __launch_bounds__(256) void perm_kernel(const float* __restrict__ We,
                                                   int* __restrict__ perm) {
    int idx = blockIdx.x * 256 + threadIdx.x;       // over 1024*1024
    if (We[idx] > 0.5f) perm[idx >> 10] = idx & 1023;
}

// Reset ticket; zero the packed-S buffers at t0==0 (kills stale tags across
// graph replays / workspace re-poison).
__global__ void ctrl_init(int* __restrict__ flags, unsigned int* __restrict__ Spub,
                          int zero_spub) {
    int i = blockIdx.x * 256 + threadIdx.x;
    if (i == 0) flags[1024] = 0;                    // ticket counter
    if (zero_spub && i < (1 << 14)) {
        Spub[i] = 0u;
        Spub[i + (1 << 14)] = 0u;
    }
}

// Persistent scan for one 128-step chunk. 1024 blocks launched; 64 workers on
// XCD 0 (ticket-selected), each block = 4 waves = 4 rows (wave w owns row
// b*4+w; lane l owns cols 4l..4l+3). Each WAVE advances autonomously: no
// barriers, no flags — it polls the tagged packed-S dwords of its 10 tap rows.
__global__ __launch_bounds__(256) void scan_chunk(
    const float* __restrict__ X,
    const int* __restrict__ perm,
    const float* __restrict__ mc,
    const float* __restrict__ mf,
    unsigned int* __restrict__ Spub,       // packed ping-pong [2][256][64]
    float* __restrict__ Vsave,             // [CELLS]
    unsigned short* __restrict__ Achunk,   // [TB][KTOT] bf16
    int* __restrict__ flags,               // ticket at [1024]
    int t0)
{
#pragma clang fp contract(off)
    __shared__ float4 C5L[4][64];   // per-wave vertical 5-sums  (wave-private)
    __shared__ float4 C9L[4][64];   // per-wave dilated 9-sums   (wave-private)
    __shared__ int sh_b;

    const int tid = threadIdx.x;
    if (tid == 0) {
        int tk = -1;
        if (xcc_id() == 0)
            tk = __hip_atomic_fetch_add(&flags[1024], 1, __ATOMIC_RELAXED,
                                        __HIP_MEMORY_SCOPE_AGENT);
        sh_b = tk;
    }
    __syncthreads();
    const int b = sh_b;
    if (b < 0 || b >= NW) return;   // uniform per block

    const int w = tid >> 6;         // wave id = row within strip
    const int l = tid & 63;         // lane = column group (cols 4l..4l+3)
    const int row = b * 4 + w;      // absolute row
    const int cy = row >> 3;        // coarse row

    // step-invariant input-gather state
    const int cc = cy * 32 + (l >> 1);
    const int pidx = perm[cc];
    const float mcv = mc[cc];

    // tap offsets (dwords) within one packed buffer (own row stays in regs)
    constexpr int DYS10[10] = {-8, -6, -4, -2, -1, 1, 2, 4, 6, 8};
    int toff[10];
#pragma unroll
    for (int i = 0; i < 10; ++i)
        toff[i] = (((row + DYS10[i]) & 255) << 6) | l;
    const int off_own = (row << 6) | l;

    // V state + fine mask + own packed S live in registers for the chunk.
    float4 V;
    const float4 mfv = *(const float4*)&mf[row * DD + 4 * l];
    unsigned int own;               // own S as 4 nibbles (low 16 bits)
    if (t0 == 0) {
        V = make_float4(0.f, 0.f, 0.f, 0.f);
        own = 0u;
    } else {
        V = *(const float4*)&Vsave[row * DD + 4 * l];
        // published at end of step t0-1 into buf[(t0-1)&1] == buf[(t0+1)&1];
        // prior kernel completion makes it visible (launch-boundary acquire).
        own = Spub[(((t0 + 1) & 1) << 14) + off_own] & 0xFFFFu;
    }

    float xv = X[(long)t0 * 1024 + pidx];   // input for the first step
    u16x4 pV = {0, 0, 0, 0};                // prev step's readout (bf16 bits)
    u16x4 pS = {0, 0, 0, 0};
    bool bailed = false;

    for (int t = t0; t < t0 + TB; ++t) {
        // 1. acquire S_{t-1} taps: buffer_inv (drop stale L1) + volatile dword
        //    loads; retry until all 10 tags match. One L2 RTT per retry.
        unsigned int tp[10];
        if (t > 0) {
            const volatile unsigned int* rbase =
                (const volatile unsigned int*)(Spub + (((t + 1) & 1) << 14));
            const unsigned int tag = (unsigned int)t;
            long g = 0;
            bool ok;
            do {
                asm volatile("buffer_inv" ::: "memory");
#pragma unroll
                for (int i = 0; i < 10; ++i) tp[i] = rbase[toff[i]];
                bool mine = true;
#pragma unroll
                for (int i = 0; i < 10; ++i) mine &= ((tp[i] >> 16) == tag);
                ok = __all(mine);
                if (++g > (1L << 18)) break;
            } while (!ok);
            if (!ok) { bailed = true; break; }   // wrong result, no hang
#pragma unroll
            for (int i = 0; i < 10; ++i) tp[i] &= 0xFFFFu;
        } else {
#pragma unroll
            for (int i = 0; i < 10; ++i) tp[i] = 0u;
        }

        // 2. flush previous step's readout (nontemporal bf16 -> no L2
        //    allocation; the stream that used to evict Spub) + X prefetch.
        if (t > t0) {
            unsigned short* Ap =
                Achunk + (long)(t - 1 - t0) * KTOT + row * DD + 4 * l;
            nt_store_bf4(Ap, pV);
            nt_store_bf4(Ap + CELLS, pS);
        }
        float xnext = X[(long)(t + 1 < TT ? t + 1 : TT - 1) * 1024 + pidx];
        const float um = tanhf(xv * mcv);

        // 3. vertical sums in nibble-int domain (counts <= 9 < 16, no carry),
        //    then convert -> floats identical to the verified float path.
        const unsigned int c5i = tp[3] + tp[4] + own + tp[5] + tp[6];
        const unsigned int c9i = tp[0] + tp[1] + tp[2] + tp[3] + own
                               + tp[6] + tp[7] + tp[8] + tp[9];
        float4 c5 = make_float4((float)(c5i & 0xFu), (float)((c5i >> 4) & 0xFu),
                                (float)((c5i >> 8) & 0xFu), (float)((c5i >> 12) & 0xFu));
        float4 c9 = make_float4((float)(c9i & 0xFu), (float)((c9i >> 4) & 0xFu),
                                (float)((c9i >> 8) & 0xFu), (float)((c9i >> 12) & 0xFu));

        // 4. wave-internal column exchange via LDS (wave-private -> no barrier)
        C5L[w][l] = c5;
        C9L[w][l] = c9;
        __builtin_amdgcn_wave_barrier();
        float4 c5m  = C5L[w][(l + 63) & 63];
        float4 c5p  = C5L[w][(l + 1) & 63];
        float4 c9m2 = C9L[w][(l + 62) & 63];
        float4 c9m1 = C9L[w][(l + 63) & 63];
        float4 c9p1 = C9L[w][(l + 1) & 63];
        float4 c9p2 = C9L[w][(l + 2) & 63];
        __builtin_amdgcn_wave_barrier();

        // 5. horizontal sums + V update (all in registers; verbatim verified)
        float e5[8] = {c5m.z, c5m.w, c5.x, c5.y, c5.z, c5.w, c5p.x, c5p.y};
        float e9[20] = {c9m2.x, c9m2.y, c9m2.z, c9m2.w,
                        c9m1.x, c9m1.y, c9m1.z, c9m1.w,
                        c9.x,   c9.y,   c9.z,   c9.w,
                        c9p1.x, c9p1.y, c9p1.z, c9p1.w,
                        c9p2.x, c9p2.y, c9p2.z, c9p2.w};
        float Vc[4]  = {V.x, V.y, V.z, V.w};
        float mfc[4] = {mfv.x, mfv.y, mfv.z, mfv.w};
        float Vn[4], Sn[4];
        unsigned int ipk = 0;
#pragma unroll
        for (int j = 0; j < 4; ++j) {
            float h5 = e5[j] + e5[j+1] + e5[j+2] + e5[j+3] + e5[j+4];
            float h9 = e9[j] + e9[j+2] + e9[j+4] + e9[j+6] + e9[j+8]
                     + e9[j+10] + e9[j+12] + e9[j+14] + e9[j+16];
            float avg5 = h5 * (1.0f/25.0f);
            float avg9 = h9 * (1.0f/81.0f);
            float lat = avg5 - 0.5f * avg9;          // EXC*avg5 + INH*avg9
            float u = um * mfc[j];                   // exact: mf in {0,1}
            float V1 = 0.9f * Vc[j] + 0.5f * u;      // DECAY*V + SPLIT*x
            float V2 = (V1 >= 0.1f) ? ((V1 + 0.5f * u) + lat) : V1;
            V2 = fminf(V2, 1.0f);
            const bool sp = V2 > 0.75f;
            Vn[j] = sp ? 0.0f : V2;
            Sn[j] = sp ? 1.0f : 0.0f;
            if (sp) ipk |= 1u << (4 * j);
        }

        // 6. publish: the tagged packed PLAIN VOLATILE store IS the release
        //    (write-through L1 -> resident in XCD-0 L2; R6's verified idiom).
        {
            volatile unsigned int* wslot =
                (volatile unsigned int*)(Spub + ((t & 1) << 14) + off_own);
            *wslot = ipk | ((unsigned int)(t + 1) << 16);
        }
        own = ipk;

        // 7. rotate registers (bf16-pack now; flush happens next iter, step 2).
        pV = (u16x4){f2bf(Vn[0]), f2bf(Vn[1]), f2bf(Vn[2]), f2bf(Vn[3])};
        pS = (u16x4){f2bf(Sn[0]), f2bf(Sn[1]), f2bf(Sn[2]), f2bf(Sn[3])};
        V = make_float4(Vn[0], Vn[1], Vn[2], Vn[3]);
        xv = xnext;
    }

    if (!bailed) {
        // flush the final step's readout
        unsigned short* Ap = Achunk + (long)(TB - 1) * KTOT + row * DD + 4 * l;
        nt_store_bf4(Ap, pV);
        nt_store_bf4(Ap + CELLS, pS);
    }

    // save V for next chunk (fp32, bit-exact recurrent state)
    *(float4*)&Vsave[row * DD + 4 * l] = V;
}

// Split-K GEMM on one chunk: 64 t x 128 o x KSLAB k per block. Grid (2, NSLAB).
// A is bf16 (expanded exactly to fp32 at staging); B and math stay fp32.
__global__ __launch_bounds__(256) void gemm_partial(
    const unsigned short* __restrict__ A,   // chunk [TB][KTOT] bf16
    const float* __restrict__ B,            // W_out [128][KTOT]
    float* __restrict__ P)                  // [NSLAB][TB][128]
{
    __shared__ float As[16][68];   // [k][t]
    __shared__ float Bs[16][132];  // [k][o]
    const int tid = threadIdx.x;
    const int t0 = blockIdx.x * 64;
    const long k0 = (long)blockIdx.y * KSLAB;
    const int tx = tid & 15;       // 8 o's each
    const int ty = tid >> 4;       // 4 t's each

    float acc[4][8];
#pragma unroll
    for (int i = 0; i < 4; ++i)
#pragma unroll
        for (int j = 0; j < 8; ++j) acc[i][j] = 0.0f;

    const int ar = tid >> 2, ac = (tid & 3) * 4;   // A: 64 rows x 16 k
    const int br = tid >> 1, bc = (tid & 1) * 8;   // B: 128 rows x 16 k

    for (int kc = 0; kc < KSLAB; kc += 16) {
        ushort4 av = *(const ushort4*)&A[(long)(t0 + ar) * KTOT + k0 + kc + ac];
        As[ac+0][ar] = bf2f(av.x); As[ac+1][ar] = bf2f(av.y);
        As[ac+2][ar] = bf2f(av.z); As[ac+3][ar] = bf2f(av.w);
        float4 bv0 = *(const float4*)&B[(long)br * KTOT + k0 + kc + bc];
        float4 bv1 = *(const float4*)&B[(long)br * KTOT + k0 + kc + bc + 4];
        Bs[bc+0][br] = bv0.x; Bs[bc+1][br] = bv0.y; Bs[bc+2][br] = bv0.z; Bs[bc+3][br] = bv0.w;
        Bs[bc+4][br] = bv1.x; Bs[bc+5][br] = bv1.y; Bs[bc+6][br] = bv1.z; Bs[bc+7][br] = bv1.w;
        __syncthreads();
#pragma unroll
        for (int kk = 0; kk < 16; ++kk) {
            float4 a4  = *(const float4*)&As[kk][ty*4];
            float4 b40 = *(const float4*)&Bs[kk][tx*8];
            float4 b41 = *(const float4*)&Bs[kk][tx*8+4];
            float a[4] = {a4.x, a4.y, a4.z, a4.w};
            float b[8] = {b40.x, b40.y, b40.z, b40.w, b41.x, b41.y, b41.z, b41.w};
#pragma unroll
            for (int i = 0; i < 4; ++i)
#pragma unroll
                for (int j = 0; j < 8; ++j) acc[i][j] += a[i] * b[j];
        }
        __syncthreads();
    }
#pragma unroll
    for (int i = 0; i < 4; ++i)
#pragma unroll
        for (int j = 0; j < 8; ++j)
            P[((long)blockIdx.y * TB + t0 + ty*4 + i) * 128 + tx*8 + j] = acc[i][j];
}

// Sum NSLAB partials for one chunk, add bias, write out rows [c*TB, (c+1)*TB).
__global__ __launch_bounds__(256) void reduce_kernel(
    const float* __restrict__ P, const float* __restrict__ bias,
    float* __restrict__ out, int c)
{
    int tid = blockIdx.x * 256 + threadIdx.x;      // 16384 = TB*128
    int o = tid & 127;
    float acc = 0.0f;
#pragma unroll 8
    for (int j = 0; j < NSLAB; ++j) acc += P[(long)j * (TB * 128) + tid];
    out[(long)c * (TB * 128) + tid] = acc + bias[o];
}

} // namespace

extern "C" void kernel_launch(void* const* d_in, const int* in_sizes, int n_in,
                              void* d_out, int out_size, void* d_ws, size_t ws_size,
                              hipStream_t stream)
{
    const float* X  = (const float*)d_in[0];   // [512,1024]
    const float* We = (const float*)d_in[1];   // [1024,1024] permuted identity
    const float* mc = (const float*)d_in[2];   // [32,32]
    const float* mf = (const float*)d_in[3];   // [256,256]
    const float* Wo = (const float*)d_in[4];   // [128,2,256,256]
    const float* bo = (const float*)d_in[5];   // [128]
    float* out = (float*)d_out;                // [512,128] fp32

    if (ws_size < (size_t)WS_REQUIRED) return;  // fail loudly (wrong result, no fault)

    char* ws = (char*)d_ws;
    int*            perm   = (int*)(ws + OFF_PERM);
    int*            flags  = (int*)(ws + OFF_FLAG);
    float*          Vsave  = (float*)(ws + OFF_VSAVE);
    unsigned int*   Spub   = (unsigned int*)(ws + OFF_S);
    unsigned short* Achunk = (unsigned short*)(ws + OFF_A);
    float*          P      = (float*)(ws + OFF_P);

    perm_kernel<<<4096, 256, 0, stream>>>(We, perm);
    for (int c = 0; c < NCH; ++c) {
        ctrl_init<<<64, 256, 0, stream>>>(flags, Spub, c == 0 ? 1 : 0);
        scan_chunk<<<1024, 256, 0, stream>>>(X, perm, mc, mf, Spub, Vsave, Achunk,
                                             flags, c * TB);
        gemm_partial<<<dim3(2, NSLAB), 256, 0, stream>>>(Achunk, Wo, P);
        reduce_kernel<<<64, 256, 0, stream>>>(P, bo, out, c);
    }
}

// Round 10
// 1397.183 us; speedup vs baseline: 1.7446x; 1.7446x over previous
//
#include <hip/hip_runtime.h>
#include <cstdint>

// Cortex reservoir: embed(perm-gather) -> single-XCD persistent wave-autonomous
// spiking scan (tagged-data sync, R8-verbatim) WITH previous-chunk GEMM fused
// onto the idle non-XCD0 blocks -> reduce.
//
// Scan sync (R3/R8, best verified: 392us/chunk, total 1801us): lane's 4 S-cells
// pack into ONE dword pk = S0|S1<<4|S2<<8|S3<<12|(t+1)<<16 (nibbles+step tag).
// Publisher's agent-scope store IS the publication; consumers poll their 10 tap
// dwords until all tags match. Tag travels WITH data -> no fences. Tap set
// {+-1,+-2,+-4,+-6,+-8} symmetric -> ping-pong race-free.
//
// R10 change (no sync-protocol edits): the scan kernel launches 1024 blocks but
// only ~64 (XCD0, ticket<64) do scan work; ~896 exit idle. Now blocks with
// xcc!=0 take a SECOND ticket and run the previous chunk's split-K GEMM
// (verbatim gemm_partial body) on a double-buffered Achunk. GEMM (~55us) hides
// under the scan (~392us); 3 standalone gemm launches vanish. Cross-kernel
// visibility of Achunk[(c-1)&1] is the same launch-boundary guarantee R8
// already relies on. Ledger note: per-step LLC sync floor measured ~385-420
// us/chunk across 3 correct protocols (R2/R8/R3); scan left untouched.
//
// ws layout (~72.4 MiB, same footprint as R0's 72.8 requirement):
//   OFF_PERM  : perm int[1024]
//   OFF_FLAG  : scan ticket at int[1024], gemm ticket at int[1025]
//   OFF_VSAVE : V snapshot float[65536]
//   OFF_S     : Spub packed ping-pong uint[2][256][64]
//   OFF_A     : A chunks bf16[2][128][131072]  (double-buffered)
//   OFF_P     : split-K partials float[128][128][128]

namespace {

constexpr int TT = 512;
constexpr int DD = 256;
constexpr int CELLS = DD * DD;              // 65536
constexpr long KTOT = 2L * CELLS;           // 131072
constexpr int TB = 128;                     // time-chunk
constexpr int NCH = TT / TB;                // 4
constexpr int KSLAB = 1024;
constexpr int NSLAB = 128;                  // KTOT / KSLAB
constexpr int NW = 64;                      // scan worker blocks (one XCD)
constexpr long ACH = (long)TB * KTOT;       // elems per A chunk

constexpr long OFF_PERM = 0;
constexpr long OFF_FLAG = 4096;
constexpr long OFF_VSAVE = OFF_FLAG + 8192;
constexpr long OFF_S = OFF_VSAVE + (long)CELLS * 4;
constexpr long OFF_A = OFF_S + 2L * CELLS * 4;
constexpr long OFF_P = OFF_A + 2L * ACH * 2;               // 2 bf16 chunks
constexpr long WS_REQUIRED = OFF_P + (long)NSLAB * TB * 128 * 4;  // ~72.4 MiB

__device__ __forceinline__ int xcc_id() {
    int x;
    asm volatile("s_getreg_b32 %0, hwreg(HW_REG_XCC_ID, 0, 4)" : "=s"(x));
    return x;
}

// fp32 -> bf16 bits, round-to-nearest-even (values are finite here).
__device__ __forceinline__ unsigned short f2bf(float x) {
    unsigned int u = __float_as_uint(x);
    u += 0x7FFFu + ((u >> 16) & 1u);
    return (unsigned short)(u >> 16);
}
// bf16 bits -> fp32 (exact).
__device__ __forceinline__ float bf2f(unsigned short b) {
    return __uint_as_float((unsigned int)b << 16);
}

__global__ __launch_bounds__(256) void perm_kernel(const float* __restrict__ We,
                                                   int* __restrict__ perm) {
    int idx = blockIdx.x * 256 + threadIdx.x;       // over 1024*1024
    if (We[idx] > 0.5f) perm[idx >> 10] = idx & 1023;
}

// Reset tickets; zero the packed-S buffers at t0==0 (kills stale tags across
// graph replays / workspace re-poison).
__global__ void ctrl_init(int* __restrict__ flags, unsigned int* __restrict__ Spub,
                          int zero_spub) {
    int i = blockIdx.x * 256 + threadIdx.x;
    if (i == 0) { flags[1024] = 0; flags[1025] = 0; }   // scan / gemm tickets
    if (zero_spub && i < (1 << 14)) {
        Spub[i] = 0u;
        Spub[i + (1 << 14)] = 0u;
    }
}

// Fused kernel, 1024 blocks x 256 threads:
//  - blocks on XCD0 with scan-ticket < 64: persistent 128-step scan (R8 verbatim)
//  - blocks with xcc != 0 and gemm-ticket < 256: one split-K GEMM tile of the
//    PREVIOUS chunk (gemm_partial verbatim; bx = gt&1, by = gt>>1)
//  - everyone else exits.
__global__ __launch_bounds__(256) void scan_gemm(
    const float* __restrict__ X,
    const int* __restrict__ perm,
    const float* __restrict__ mc,
    const float* __restrict__ mf,
    unsigned int* __restrict__ Spub,       // packed ping-pong [2][256][64]
    float* __restrict__ Vsave,             // [CELLS]
    unsigned short* __restrict__ Awr,      // this chunk's A [TB][KTOT] bf16
    int* __restrict__ flags,               // tickets at [1024],[1025]
    int t0,
    const unsigned short* __restrict__ Ard,  // prev chunk's A (gemm input)
    const float* __restrict__ B,             // W_out [128][KTOT]
    float* __restrict__ P,                   // [NSLAB][TB][128]
    int gemm_on)
{
#pragma clang fp contract(off)
    __shared__ float4 C5L[4][64];   // scan: per-wave vertical 5-sums
    __shared__ float4 C9L[4][64];   // scan: per-wave dilated 9-sums
    __shared__ float As[16][68];    // gemm: [k][t]
    __shared__ float Bs[16][132];   // gemm: [k][o]
    __shared__ int sh_b;
    __shared__ int sh_g;

    const int tid = threadIdx.x;
    const int xcc = xcc_id();
    if (tid == 0) {
        int tk = -1, gk = -1;
        if (xcc == 0)
            tk = __hip_atomic_fetch_add(&flags[1024], 1, __ATOMIC_RELAXED,
                                        __HIP_MEMORY_SCOPE_AGENT);
        else if (gemm_on)
            gk = __hip_atomic_fetch_add(&flags[1025], 1, __ATOMIC_RELAXED,
                                        __HIP_MEMORY_SCOPE_AGENT);
        sh_b = tk;
        sh_g = gk;
    }
    __syncthreads();
    const int b = sh_b;
    const int gt = sh_g;

    if (b >= 0 && b < NW) {
        // ---------------- scan path (R8 verbatim) ----------------
        const int w = tid >> 6;         // wave id = row within strip
        const int l = tid & 63;         // lane = column group (cols 4l..4l+3)
        const int row = b * 4 + w;      // absolute row
        const int cy = row >> 3;        // coarse row

        const int cc = cy * 32 + (l >> 1);
        const int pidx = perm[cc];
        const float mcv = mc[cc];

        constexpr int DYS10[10] = {-8, -6, -4, -2, -1, 1, 2, 4, 6, 8};
        int toff[10];
#pragma unroll
        for (int i = 0; i < 10; ++i)
            toff[i] = (((row + DYS10[i]) & 255) << 6) | l;

        float4 V;
        const float4 mfv = *(const float4*)&mf[row * DD + 4 * l];
        unsigned int own;               // own S as 4 nibbles (low 16 bits)
        if (t0 == 0) {
            V = make_float4(0.f, 0.f, 0.f, 0.f);
            own = 0u;
        } else {
            V = *(const float4*)&Vsave[row * DD + 4 * l];
            own = Spub[(((t0 + 1) & 1) << 14) + (row << 6) + l] & 0xFFFFu;
        }

        for (int t = t0; t < t0 + TB; ++t) {
            // 1. acquire S_{t-1} taps: poll tagged dwords.
            unsigned int tp[10];
            if (t > 0) {
                const unsigned int* base = Spub + (((t + 1) & 1) << 14);
                const unsigned int tag = (unsigned int)t;
                long g = 0;
                bool ok;
                do {
#pragma unroll
                    for (int i = 0; i < 10; ++i)
                        tp[i] = __hip_atomic_load(&base[toff[i]], __ATOMIC_RELAXED,
                                                  __HIP_MEMORY_SCOPE_AGENT);
                    bool mine = true;
#pragma unroll
                    for (int i = 0; i < 10; ++i) mine &= ((tp[i] >> 16) == tag);
                    ok = __all(mine);
                    if (++g > (1L << 18)) break;
                } while (!ok);
                if (!ok) break;   // bail: wrong result, no hang
#pragma unroll
                for (int i = 0; i < 10; ++i) tp[i] &= 0xFFFFu;
            } else {
#pragma unroll
                for (int i = 0; i < 10; ++i) tp[i] = 0u;
            }

            // 2. input drive (exact: mc in {0,1})
            const float um = tanhf(X[(long)t * 1024 + pidx] * mcv);

            // 3. vertical sums in nibble-int domain (carry-free, exact).
            const unsigned int c5i = tp[3] + tp[4] + own + tp[5] + tp[6];
            const unsigned int c9i = tp[0] + tp[1] + tp[2] + tp[3] + own
                                   + tp[6] + tp[7] + tp[8] + tp[9];
            float4 c5 = make_float4((float)(c5i & 0xFu), (float)((c5i >> 4) & 0xFu),
                                    (float)((c5i >> 8) & 0xFu), (float)((c5i >> 12) & 0xFu));
            float4 c9 = make_float4((float)(c9i & 0xFu), (float)((c9i >> 4) & 0xFu),
                                    (float)((c9i >> 8) & 0xFu), (float)((c9i >> 12) & 0xFu));

            // 4. wave-internal column exchange via LDS (wave-private).
            C5L[w][l] = c5;
            C9L[w][l] = c9;
            __builtin_amdgcn_wave_barrier();
            float4 c5m  = C5L[w][(l + 63) & 63];
            float4 c5p  = C5L[w][(l + 1) & 63];
            float4 c9m2 = C5L[w][0].x == 0 && false ? c5 : C9L[w][(l + 62) & 63];
            c9m2 = C9L[w][(l + 62) & 63];
            float4 c9m1 = C9L[w][(l + 63) & 63];
            float4 c9p1 = C9L[w][(l + 1) & 63];
            float4 c9p2 = C9L[w][(l + 2) & 63];
            __builtin_amdgcn_wave_barrier();

            // 5. horizontal sums + V update (verbatim verified math).
            float e5[8] = {c5m.z, c5m.w, c5.x, c5.y, c5.z, c5.w, c5p.x, c5p.y};
            float e9[20] = {c9m2.x, c9m2.y, c9m2.z, c9m2.w,
                            c9m1.x, c9m1.y, c9m1.z, c9m1.w,
                            c9.x,   c9.y,   c9.z,   c9.w,
                            c9p1.x, c9p1.y, c9p1.z, c9p1.w,
                            c9p2.x, c9p2.y, c9p2.z, c9p2.w};
            float Vc[4]  = {V.x, V.y, V.z, V.w};
            float mfc[4] = {mfv.x, mfv.y, mfv.z, mfv.w};
            float Vn[4], Sn[4];
            unsigned int ipk = 0;
#pragma unroll
            for (int j = 0; j < 4; ++j) {
                float h5 = e5[j] + e5[j+1] + e5[j+2] + e5[j+3] + e5[j+4];
                float h9 = e9[j] + e9[j+2] + e9[j+4] + e9[j+6] + e9[j+8]
                         + e9[j+10] + e9[j+12] + e9[j+14] + e9[j+16];
                float avg5 = h5 * (1.0f/25.0f);
                float avg9 = h9 * (1.0f/81.0f);
                float lat = avg5 - 0.5f * avg9;          // EXC*avg5 + INH*avg9
                float u = um * mfc[j];                   // exact: mf in {0,1}
                float V1 = 0.9f * Vc[j] + 0.5f * u;      // DECAY*V + SPLIT*x
                float V2 = (V1 >= 0.1f) ? ((V1 + 0.5f * u) + lat) : V1;
                V2 = fminf(V2, 1.0f);
                const bool sp = V2 > 0.75f;
                Vn[j] = sp ? 0.0f : V2;
                Sn[j] = sp ? 1.0f : 0.0f;
                if (sp) ipk |= 1u << (4 * j);
            }

            // 6. publish: the tagged packed store IS the release.
            __hip_atomic_store(&Spub[((t & 1) << 14) + (row << 6) + l],
                               ipk | ((unsigned int)(t + 1) << 16),
                               __ATOMIC_RELAXED, __HIP_MEMORY_SCOPE_AGENT);
            own = ipk;

            // 7. off-critical-path: readout rows in bf16.
            unsigned short* Arow = Awr + (long)(t - t0) * KTOT;
            ushort4 uv, us;
            uv.x = f2bf(Vn[0]); uv.y = f2bf(Vn[1]); uv.z = f2bf(Vn[2]); uv.w = f2bf(Vn[3]);
            us.x = f2bf(Sn[0]); us.y = f2bf(Sn[1]); us.z = f2bf(Sn[2]); us.w = f2bf(Sn[3]);
            *(ushort4*)&Arow[row * DD + 4 * l] = uv;
            *(ushort4*)&Arow[CELLS + row * DD + 4 * l] = us;
            V = make_float4(Vn[0], Vn[1], Vn[2], Vn[3]);
        }

        // save V for next chunk (fp32, bit-exact recurrent state)
        *(float4*)&Vsave[row * DD + 4 * l] = V;
        return;
    }

    if (gt >= 0 && gt < 2 * NSLAB) {
        // ---------------- gemm path (gemm_partial verbatim) ----------------
        const int t0g = (gt & 1) * 64;
        const long k0 = (long)(gt >> 1) * KSLAB;
        const int tx = tid & 15;       // 8 o's each
        const int ty = tid >> 4;       // 4 t's each

        float acc[4][8];
#pragma unroll
        for (int i = 0; i < 4; ++i)
#pragma unroll
            for (int j = 0; j < 8; ++j) acc[i][j] = 0.0f;

        const int ar = tid >> 2, ac = (tid & 3) * 4;   // A: 64 rows x 16 k
        const int br = tid >> 1, bc = (tid & 1) * 8;   // B: 128 rows x 16 k

        for (int kc = 0; kc < KSLAB; kc += 16) {
            ushort4 av = *(const ushort4*)&Ard[(long)(t0g + ar) * KTOT + k0 + kc + ac];
            As[ac+0][ar] = bf2f(av.x); As[ac+1][ar] = bf2f(av.y);
            As[ac+2][ar] = bf2f(av.z); As[ac+3][ar] = bf2f(av.w);
            float4 bv0 = *(const float4*)&B[(long)br * KTOT + k0 + kc + bc];
            float4 bv1 = *(const float4*)&B[(long)br * KTOT + k0 + kc + bc + 4];
            Bs[bc+0][br] = bv0.x; Bs[bc+1][br] = bv0.y; Bs[bc+2][br] = bv0.z; Bs[bc+3][br] = bv0.w;
            Bs[bc+4][br] = bv1.x; Bs[bc+5][br] = bv1.y; Bs[bc+6][br] = bv1.z; Bs[bc+7][br] = bv1.w;
            __syncthreads();
#pragma unroll
            for (int kk = 0; kk < 16; ++kk) {
                float4 a4  = *(const float4*)&As[kk][ty*4];
                float4 b40 = *(const float4*)&Bs[kk][tx*8];
                float4 b41 = *(const float4*)&Bs[kk][tx*8+4];
                float a[4] = {a4.x, a4.y, a4.z, a4.w};
                float bb[8] = {b40.x, b40.y, b40.z, b40.w, b41.x, b41.y, b41.z, b41.w};
#pragma unroll
                for (int i = 0; i < 4; ++i)
#pragma unroll
                    for (int j = 0; j < 8; ++j) acc[i][j] += a[i] * bb[j];
            }
            __syncthreads();
        }
#pragma unroll
        for (int i = 0; i < 4; ++i)
#pragma unroll
            for (int j = 0; j < 8; ++j)
                P[((long)(gt >> 1) * TB + t0g + ty*4 + i) * 128 + tx*8 + j] = acc[i][j];
    }
}

// Standalone split-K GEMM (used for the final chunk only; verbatim verified).
__global__ __launch_bounds__(256) void gemm_partial(
    const unsigned short* __restrict__ A,   // chunk [TB][KTOT] bf16
    const float* __restrict__ B,            // W_out [128][KTOT]
    float* __restrict__ P)                  // [NSLAB][TB][128]
{
    __shared__ float As[16][68];   // [k][t]
    __shared__ float Bs[16][132];  // [k][o]
    const int tid = threadIdx.x;
    const int t0 = blockIdx.x * 64;
    const long k0 = (long)blockIdx.y * KSLAB;
    const int tx = tid & 15;       // 8 o's each
    const int ty = tid >> 4;       // 4 t's each

    float acc[4][8];
#pragma unroll
    for (int i = 0; i < 4; ++i)
#pragma unroll
        for (int j = 0; j < 8; ++j) acc[i][j] = 0.0f;

    const int ar = tid >> 2, ac = (tid & 3) * 4;   // A: 64 rows x 16 k
    const int br = tid >> 1, bc = (tid & 1) * 8;   // B: 128 rows x 16 k

    for (int kc = 0; kc < KSLAB; kc += 16) {
        ushort4 av = *(const ushort4*)&A[(long)(t0 + ar) * KTOT + k0 + kc + ac];
        As[ac+0][ar] = bf2f(av.x); As[ac+1][ar] = bf2f(av.y);
        As[ac+2][ar] = bf2f(av.z); As[ac+3][ar] = bf2f(av.w);
        float4 bv0 = *(const float4*)&B[(long)br * KTOT + k0 + kc + bc];
        float4 bv1 = *(const float4*)&B[(long)br * KTOT + k0 + kc + bc + 4];
        Bs[bc+0][br] = bv0.x; Bs[bc+1][br] = bv0.y; Bs[bc+2][br] = bv0.z; Bs[bc+3][br] = bv0.w;
        Bs[bc+4][br] = bv1.x; Bs[bc+5][br] = bv1.y; Bs[bc+6][br] = bv1.z; Bs[bc+7][br] = bv1.w;
        __syncthreads();
#pragma unroll
        for (int kk = 0; kk < 16; ++kk) {
            float4 a4  = *(const float4*)&As[kk][ty*4];
            float4 b40 = *(const float4*)&Bs[kk][tx*8];
            float4 b41 = *(const float4*)&Bs[kk][tx*8+4];
            float a[4] = {a4.x, a4.y, a4.z, a4.w};
            float b[8] = {b40.x, b40.y, b40.z, b40.w, b41.x, b41.y, b41.z, b41.w};
#pragma unroll
            for (int i = 0; i < 4; ++i)
#pragma unroll
                for (int j = 0; j < 8; ++j) acc[i][j] += a[i] * b[j];
        }
        __syncthreads();
    }
#pragma unroll
    for (int i = 0; i < 4; ++i)
#pragma unroll
        for (int j = 0; j < 8; ++j)
            P[((long)blockIdx.y * TB + t0 + ty*4 + i) * 128 + tx*8 + j] = acc[i][j];
}

// Sum NSLAB partials for one chunk, add bias, write out rows [c*TB, (c+1)*TB).
__global__ __launch_bounds__(256) void reduce_kernel(
    const float* __restrict__ P, const float* __restrict__ bias,
    float* __restrict__ out, int c)
{
    int tid = blockIdx.x * 256 + threadIdx.x;      // 16384 = TB*128
    int o = tid & 127;
    float acc = 0.0f;
#pragma unroll 8
    for (int j = 0; j < NSLAB; ++j) acc += P[(long)j * (TB * 128) + tid];
    out[(long)c * (TB * 128) + tid] = acc + bias[o];
}

} // namespace

extern "C" void kernel_launch(void* const* d_in, const int* in_sizes, int n_in,
                              void* d_out, int out_size, void* d_ws, size_t ws_size,
                              hipStream_t stream)
{
    const float* X  = (const float*)d_in[0];   // [512,1024]
    const float* We = (const float*)d_in[1];   // [1024,1024] permuted identity
    const float* mc = (const float*)d_in[2];   // [32,32]
    const float* mf = (const float*)d_in[3];   // [256,256]
    const float* Wo = (const float*)d_in[4];   // [128,2,256,256]
    const float* bo = (const float*)d_in[5];   // [128]
    float* out = (float*)d_out;                // [512,128] fp32

    if (ws_size < (size_t)WS_REQUIRED) return;  // fail loudly (wrong result, no fault)

    char* ws = (char*)d_ws;
    int*            perm   = (int*)(ws + OFF_PERM);
    int*            flags  = (int*)(ws + OFF_FLAG);
    float*          Vsave  = (float*)(ws + OFF_VSAVE);
    unsigned int*   Spub   = (unsigned int*)(ws + OFF_S);
    unsigned short* Achunk = (unsigned short*)(ws + OFF_A);
    float*          P      = (float*)(ws + OFF_P);

    perm_kernel<<<4096, 256, 0, stream>>>(We, perm);
    for (int c = 0; c < NCH; ++c) {
        ctrl_init<<<64, 256, 0, stream>>>(flags, Spub, c == 0 ? 1 : 0);
        scan_gemm<<<1024, 256, 0, stream>>>(
            X, perm, mc, mf, Spub, Vsave,
            Achunk + (long)(c & 1) * ACH,           // scan writes chunk c
            flags, c * TB,
            Achunk + (long)((c + 1) & 1) * ACH,     // gemm reads chunk c-1
            Wo, P, c > 0 ? 1 : 0);
        if (c > 0)
            reduce_kernel<<<64, 256, 0, stream>>>(P, bo, out, c - 1);
    }
    gemm_partial<<<dim3(2, NSLAB), 256, 0, stream>>>(
        Achunk + (long)((NCH - 1) & 1) * ACH, Wo, P);
    reduce_kernel<<<64, 256, 0, stream>>>(P, bo, out, NCH - 1);
}